// Round 11
// baseline (254.687 us; speedup 1.0000x reference)
//
#include <hip/hip_runtime.h>

#define N_NODES 10000
#define BN_TOT  40000
#define HID     64
#define IN_F    16
#define TCH     32
#define NW      12
#define RSTRIDE 192   // floats per row: planes [t=3][ch=64] at +0B, +256B, +512B

// ---------------- histogram of dst (degree = cnt + 1) ------------------------
__global__ void hist_kernel(const int* __restrict__ dst, int* __restrict__ cnt, int E) {
    int e = blockIdx.x * blockDim.x + threadIdx.x;
    if (e < E) atomicAdd(&cnt[dst[e]], 1);
}

// ---------------- single-block exclusive scan over 10000 bins ----------------
__global__ __launch_bounds__(1024) void scan_kernel(const int* __restrict__ cnt,
                                                    int* __restrict__ row_ptr,
                                                    int* __restrict__ fill_pos,
                                                    float* __restrict__ dinv) {
    __shared__ int part[1024];
    int t = threadIdx.x;
    int base = t * 10;
    int s = 0;
#pragma unroll
    for (int k = 0; k < 10; ++k) {
        int b = base + k;
        if (b < N_NODES) s += cnt[b];
    }
    part[t] = s;
    __syncthreads();
    for (int off = 1; off < 1024; off <<= 1) {
        int v = 0;
        if (t >= off) v = part[t - off];
        __syncthreads();
        part[t] += v;
        __syncthreads();
    }
    int running = (t == 0) ? 0 : part[t - 1];
#pragma unroll
    for (int k = 0; k < 10; ++k) {
        int b = base + k;
        if (b < N_NODES) {
            row_ptr[b]  = running;
            fill_pos[b] = running;
            int c = cnt[b];
            dinv[b] = rsqrtf((float)c + 1.0f);
            running += c;
        }
    }
    if (t == 1023) row_ptr[N_NODES] = part[1023];
}

// ---------------- CSR bucket fill: edge record = {src byte offset, ne} -------
__global__ void fill_kernel(const int* __restrict__ src, const int* __restrict__ dst,
                            const float* __restrict__ dinv,
                            int* __restrict__ fill_pos,
                            int2* __restrict__ edges, int E) {
    int e = blockIdx.x * blockDim.x + threadIdx.x;
    if (e >= E) return;
    int s = src[e], d = dst[e];
    int pos = atomicAdd(&fill_pos[d], 1);
    edges[pos] = make_int2(s * (RSTRIDE * 4), __float_as_int(dinv[s] * dinv[d]));
}

// ---------------- pack conv weights: float4 / float2 per (ic, tc) ------------
__global__ void prep_kernel(const float* __restrict__ c1w, const float* __restrict__ c2w,
                            float4* __restrict__ w1p, float2* __restrict__ w2p) {
    int idx = blockIdx.x * blockDim.x + threadIdx.x;   // 3072 threads
    if (idx < 2048) {
        int tc = idx & 31, ic = idx >> 5;
        const float* p = c1w + tc * 192 + ic * 3;
        w1p[idx] = make_float4(p[0], p[1], p[2], 0.f);
    } else {
        int i2 = idx - 2048;
        int tc = i2 & 31, ic = i2 >> 5;
        const float* p = c2w + tc * 96 + ic * 3;
        w2p[i2] = make_float2(p[0], p[1]);
    }
}

// ---------------- GEMM1 (rows < N_NODES): m[bn][t][64] = x @ W1 --------------
__global__ __launch_bounds__(256) void gemm1_kernel(const float* __restrict__ x,
                                                    const float* __restrict__ W1,
                                                    float* __restrict__ m) {
    int idx = blockIdx.x * blockDim.x + threadIdx.x;   // 640,000 threads
    int oc = idx & 63;
    int n = __builtin_amdgcn_readfirstlane(idx >> 6);  // row < 10000, b = 0
    const float* xb = x + (size_t)n * IN_F;
    float s0 = 0.f, s1 = 0.f, s2 = 0.f;
#pragma unroll
    for (int f = 0; f < IN_F; ++f) {
        float wv = W1[f * HID + oc];
        s0 += xb[(size_t)9  * N_NODES * IN_F + f] * wv;
        s1 += xb[(size_t)10 * N_NODES * IN_F + f] * wv;
        s2 += xb[(size_t)11 * N_NODES * IN_F + f] * wv;
    }
    float* mr = m + (size_t)n * RSTRIDE;
    mr[oc] = s0; mr[64 + oc] = s1; mr[128 + oc] = s2;
}

// ---- gatherA (rows < N_NODES): h1 = relu(agg+self+b1); m2 = h1 @ W2 ---------
__global__ __launch_bounds__(256, 8) void gatherA_kernel(
        const float* __restrict__ m, const int* __restrict__ row_ptr,
        const int2* __restrict__ edges,
        const float* __restrict__ dinv, const float* __restrict__ b1,
        const float* __restrict__ W2, float* __restrict__ m2) {
    __shared__ float hs[4][3][HID];
    int gid = blockIdx.x * blockDim.x + threadIdx.x;   // 10000 waves
    int lane = threadIdx.x & 63;
    int wv = threadIdx.x >> 6;
    int row = __builtin_amdgcn_readfirstlane(gid >> 6);
    const int lo0 = lane * 4, lo1 = 256 + lane * 4, lo2 = 512 + lane * 4;
    const char* mrow = (const char*)m + (size_t)row * (RSTRIDE * 4);
    float dv = dinv[row];
    float sn = dv * dv;
    float s0 = sn * *(const float*)(mrow + lo0);
    float s1 = sn * *(const float*)(mrow + lo1);
    float s2 = sn * *(const float*)(mrow + lo2);
    int j = row_ptr[row], end = row_ptr[row + 1];
    for (; j + 3 < end; j += 4) {
        int2 e0 = edges[j], e1 = edges[j + 1], e2 = edges[j + 2], e3 = edges[j + 3];
        const char* q0 = (const char*)m + e0.x;
        const char* q1 = (const char*)m + e1.x;
        const char* q2 = (const char*)m + e2.x;
        const char* q3 = (const char*)m + e3.x;
        float w0 = __int_as_float(e0.y), w1 = __int_as_float(e1.y);
        float w2 = __int_as_float(e2.y), w3 = __int_as_float(e3.y);
        s0 += w0 * *(const float*)(q0 + lo0) + w1 * *(const float*)(q1 + lo0)
            + w2 * *(const float*)(q2 + lo0) + w3 * *(const float*)(q3 + lo0);
        s1 += w0 * *(const float*)(q0 + lo1) + w1 * *(const float*)(q1 + lo1)
            + w2 * *(const float*)(q2 + lo1) + w3 * *(const float*)(q3 + lo1);
        s2 += w0 * *(const float*)(q0 + lo2) + w1 * *(const float*)(q1 + lo2)
            + w2 * *(const float*)(q2 + lo2) + w3 * *(const float*)(q3 + lo2);
    }
    for (; j < end; ++j) {
        int2 e = edges[j];
        const char* q = (const char*)m + e.x;
        float w = __int_as_float(e.y);
        s0 += w * *(const float*)(q + lo0);
        s1 += w * *(const float*)(q + lo1);
        s2 += w * *(const float*)(q + lo2);
    }
    float bb = b1[lane];
    hs[wv][0][lane] = fmaxf(s0 + bb, 0.f);
    hs[wv][1][lane] = fmaxf(s1 + bb, 0.f);
    hs[wv][2][lane] = fmaxf(s2 + bb, 0.f);
    __builtin_amdgcn_wave_barrier();
    const float4* h0v = (const float4*)&hs[wv][0][0];
    const float4* h1v = (const float4*)&hs[wv][1][0];
    const float4* h2v = (const float4*)&hs[wv][2][0];
    float t0 = 0.f, t1 = 0.f, t2 = 0.f;
#pragma unroll
    for (int ic4 = 0; ic4 < 16; ++ic4) {
        float4 h0 = h0v[ic4], h1 = h1v[ic4], h2 = h2v[ic4];
        float wA = W2[(ic4 * 4 + 0) * HID + lane];
        float wB = W2[(ic4 * 4 + 1) * HID + lane];
        float wC = W2[(ic4 * 4 + 2) * HID + lane];
        float wD = W2[(ic4 * 4 + 3) * HID + lane];
        t0 += h0.x * wA + h0.y * wB + h0.z * wC + h0.w * wD;
        t1 += h1.x * wA + h1.y * wB + h1.z * wC + h1.w * wD;
        t2 += h2.x * wA + h2.y * wB + h2.z * wC + h2.w * wD;
    }
    float* m2r = m2 + (size_t)row * RSTRIDE;
    m2r[lane] = t0; m2r[64 + lane] = t1; m2r[128 + lane] = t2;
}

// ---- gatherBconv (rows < N_NODES): H=relu(agg+self+b2), conv1+conv2+fc ------
__global__ __launch_bounds__(256, 8) void gatherBconv_kernel(
        const float* __restrict__ m, const int* __restrict__ row_ptr,
        const int2* __restrict__ edges,
        const float* __restrict__ dinv, const float* __restrict__ b2,
        const float4* __restrict__ w1p, const float* __restrict__ b1c,
        const float2* __restrict__ w2p, const float* __restrict__ b2c,
        const float* __restrict__ fcw, const float* __restrict__ fcb,
        float* __restrict__ out) {
    __shared__ float hs[4][4][HID];      // planes 0..2 = H@t9,10,11; plane 3 = zeros
    __shared__ float c1s[4][2][TCH];
    int gid = blockIdx.x * blockDim.x + threadIdx.x;   // 10000 waves
    int lane = threadIdx.x & 63;
    int wv = threadIdx.x >> 6;
    int row = __builtin_amdgcn_readfirstlane(gid >> 6);
    const int lo0 = lane * 4, lo1 = 256 + lane * 4, lo2 = 512 + lane * 4;
    const char* mrow = (const char*)m + (size_t)row * (RSTRIDE * 4);
    float dv = dinv[row];
    float sn = dv * dv;
    float s0 = sn * *(const float*)(mrow + lo0);
    float s1 = sn * *(const float*)(mrow + lo1);
    float s2 = sn * *(const float*)(mrow + lo2);
    int j = row_ptr[row], end = row_ptr[row + 1];
    for (; j + 3 < end; j += 4) {
        int2 e0 = edges[j], e1 = edges[j + 1], e2 = edges[j + 2], e3 = edges[j + 3];
        const char* q0 = (const char*)m + e0.x;
        const char* q1 = (const char*)m + e1.x;
        const char* q2 = (const char*)m + e2.x;
        const char* q3 = (const char*)m + e3.x;
        float w0 = __int_as_float(e0.y), w1 = __int_as_float(e1.y);
        float w2 = __int_as_float(e2.y), w3 = __int_as_float(e3.y);
        s0 += w0 * *(const float*)(q0 + lo0) + w1 * *(const float*)(q1 + lo0)
            + w2 * *(const float*)(q2 + lo0) + w3 * *(const float*)(q3 + lo0);
        s1 += w0 * *(const float*)(q0 + lo1) + w1 * *(const float*)(q1 + lo1)
            + w2 * *(const float*)(q2 + lo1) + w3 * *(const float*)(q3 + lo1);
        s2 += w0 * *(const float*)(q0 + lo2) + w1 * *(const float*)(q1 + lo2)
            + w2 * *(const float*)(q2 + lo2) + w3 * *(const float*)(q3 + lo2);
    }
    for (; j < end; ++j) {
        int2 e = edges[j];
        const char* q = (const char*)m + e.x;
        float w = __int_as_float(e.y);
        s0 += w * *(const float*)(q + lo0);
        s1 += w * *(const float*)(q + lo1);
        s2 += w * *(const float*)(q + lo2);
    }
    float bb = b2[lane];
    hs[wv][0][lane] = fmaxf(s0 + bb, 0.f);
    hs[wv][1][lane] = fmaxf(s1 + bb, 0.f);
    hs[wv][2][lane] = fmaxf(s2 + bb, 0.f);
    hs[wv][3][lane] = 0.f;
    __builtin_amdgcn_wave_barrier();

    int pos = lane >> 5, tc = lane & 31;
    const float4* hAv = (const float4*)&hs[wv][pos][0];
    const float4* hBv = (const float4*)&hs[wv][pos + 1][0];
    const float4* hCv = (const float4*)&hs[wv][(pos == 0) ? 2 : 3][0];
    float acc = b1c[tc];
#pragma unroll
    for (int ic4 = 0; ic4 < 16; ++ic4) {
        float4 hA = hAv[ic4], hB = hBv[ic4], hC = hCv[ic4];
        float4 wa = w1p[(ic4 * 4 + 0) * 32 + tc];
        float4 wb = w1p[(ic4 * 4 + 1) * 32 + tc];
        float4 wc = w1p[(ic4 * 4 + 2) * 32 + tc];
        float4 wd = w1p[(ic4 * 4 + 3) * 32 + tc];
        acc += hA.x * wa.x + hB.x * wa.y + hC.x * wa.z;
        acc += hA.y * wb.x + hB.y * wb.y + hC.y * wb.z;
        acc += hA.z * wc.x + hB.z * wc.y + hC.z * wc.z;
        acc += hA.w * wd.x + hB.w * wd.y + hC.w * wd.z;
    }
    c1s[wv][pos][tc] = fmaxf(acc, 0.f);
    __builtin_amdgcn_wave_barrier();

    float r = 0.f;
    if (pos == 0) {
        const float4* cAv = (const float4*)&c1s[wv][0][0];
        const float4* cBv = (const float4*)&c1s[wv][1][0];
        float a2 = b2c[tc];
#pragma unroll
        for (int ic4 = 0; ic4 < 8; ++ic4) {
            float4 cA = cAv[ic4], cB = cBv[ic4];
            float2 w0 = w2p[(ic4 * 4 + 0) * 32 + tc];
            float2 w1 = w2p[(ic4 * 4 + 1) * 32 + tc];
            float2 w2v = w2p[(ic4 * 4 + 2) * 32 + tc];
            float2 w3 = w2p[(ic4 * 4 + 3) * 32 + tc];
            a2 += cA.x * w0.x + cB.x * w0.y;
            a2 += cA.y * w1.x + cB.y * w1.y;
            a2 += cA.z * w2v.x + cB.z * w2v.y;
            a2 += cA.w * w3.x + cB.w * w3.y;
        }
        r = fmaxf(a2, 0.f) * fcw[tc];
    }
#pragma unroll
    for (int off = 16; off > 0; off >>= 1) r += __shfl_down(r, off);
    if (lane == 0) out[row] = r + fcb[0];
}

// ---- fusedTail (rows >= N_NODES): x -> gemm1 -> relu -> W2 -> relu -> conv -> fc
// No graph (deg=1, agg=0), no global intermediates. One wave per row.
__global__ __launch_bounds__(256, 8) void fusedTail_kernel(
        const float* __restrict__ x, const float* __restrict__ W1,
        const float* __restrict__ b1, const float* __restrict__ W2,
        const float* __restrict__ b2,
        const float4* __restrict__ w1p, const float* __restrict__ b1c,
        const float2* __restrict__ w2p, const float* __restrict__ b2c,
        const float* __restrict__ fcw, const float* __restrict__ fcb,
        float* __restrict__ out) {
    __shared__ float hs[4][4][HID];
    __shared__ float c1s[4][2][TCH];
    int gid = blockIdx.x * blockDim.x + threadIdx.x;   // 30000 waves
    int lane = threadIdx.x & 63;
    int wv = threadIdx.x >> 6;
    int row = __builtin_amdgcn_readfirstlane(gid >> 6) + N_NODES;  // 10000..39999
    int b = row / N_NODES, n = row - b * N_NODES;
    const float* xb = x + ((size_t)b * NW) * N_NODES * IN_F + (size_t)n * IN_F;
    float s0 = 0.f, s1 = 0.f, s2 = 0.f;
#pragma unroll
    for (int f = 0; f < IN_F; ++f) {
        float wv1 = W1[f * HID + lane];
        s0 += xb[(size_t)9  * N_NODES * IN_F + f] * wv1;
        s1 += xb[(size_t)10 * N_NODES * IN_F + f] * wv1;
        s2 += xb[(size_t)11 * N_NODES * IN_F + f] * wv1;
    }
    float bb1 = b1[lane];
    hs[wv][0][lane] = fmaxf(s0 + bb1, 0.f);   // h1 @ t=9,10,11
    hs[wv][1][lane] = fmaxf(s1 + bb1, 0.f);
    hs[wv][2][lane] = fmaxf(s2 + bb1, 0.f);
    __builtin_amdgcn_wave_barrier();
    const float4* h0v = (const float4*)&hs[wv][0][0];
    const float4* h1v = (const float4*)&hs[wv][1][0];
    const float4* h2v = (const float4*)&hs[wv][2][0];
    float t0 = 0.f, t1 = 0.f, t2 = 0.f;
#pragma unroll
    for (int ic4 = 0; ic4 < 16; ++ic4) {
        float4 h0 = h0v[ic4], h1 = h1v[ic4], h2 = h2v[ic4];
        float wA = W2[(ic4 * 4 + 0) * HID + lane];
        float wB = W2[(ic4 * 4 + 1) * HID + lane];
        float wC = W2[(ic4 * 4 + 2) * HID + lane];
        float wD = W2[(ic4 * 4 + 3) * HID + lane];
        t0 += h0.x * wA + h0.y * wB + h0.z * wC + h0.w * wD;
        t1 += h1.x * wA + h1.y * wB + h1.z * wC + h1.w * wD;
        t2 += h2.x * wA + h2.y * wB + h2.z * wC + h2.w * wD;
    }
    __builtin_amdgcn_wave_barrier();          // all hs reads done before overwrite
    float bb2 = b2[lane];
    hs[wv][0][lane] = fmaxf(t0 + bb2, 0.f);   // H @ t=9,10,11
    hs[wv][1][lane] = fmaxf(t1 + bb2, 0.f);
    hs[wv][2][lane] = fmaxf(t2 + bb2, 0.f);
    hs[wv][3][lane] = 0.f;
    __builtin_amdgcn_wave_barrier();

    int pos = lane >> 5, tc = lane & 31;
    const float4* hAv = (const float4*)&hs[wv][pos][0];
    const float4* hBv = (const float4*)&hs[wv][pos + 1][0];
    const float4* hCv = (const float4*)&hs[wv][(pos == 0) ? 2 : 3][0];
    float acc = b1c[tc];
#pragma unroll
    for (int ic4 = 0; ic4 < 16; ++ic4) {
        float4 hA = hAv[ic4], hB = hBv[ic4], hC = hCv[ic4];
        float4 wa = w1p[(ic4 * 4 + 0) * 32 + tc];
        float4 wb = w1p[(ic4 * 4 + 1) * 32 + tc];
        float4 wc = w1p[(ic4 * 4 + 2) * 32 + tc];
        float4 wd = w1p[(ic4 * 4 + 3) * 32 + tc];
        acc += hA.x * wa.x + hB.x * wa.y + hC.x * wa.z;
        acc += hA.y * wb.x + hB.y * wb.y + hC.y * wb.z;
        acc += hA.z * wc.x + hB.z * wc.y + hC.z * wc.z;
        acc += hA.w * wd.x + hB.w * wd.y + hC.w * wd.z;
    }
    c1s[wv][pos][tc] = fmaxf(acc, 0.f);
    __builtin_amdgcn_wave_barrier();

    float r = 0.f;
    if (pos == 0) {
        const float4* cAv = (const float4*)&c1s[wv][0][0];
        const float4* cBv = (const float4*)&c1s[wv][1][0];
        float a2 = b2c[tc];
#pragma unroll
        for (int ic4 = 0; ic4 < 8; ++ic4) {
            float4 cA = cAv[ic4], cB = cBv[ic4];
            float2 w0 = w2p[(ic4 * 4 + 0) * 32 + tc];
            float2 w1 = w2p[(ic4 * 4 + 1) * 32 + tc];
            float2 w2v = w2p[(ic4 * 4 + 2) * 32 + tc];
            float2 w3 = w2p[(ic4 * 4 + 3) * 32 + tc];
            a2 += cA.x * w0.x + cB.x * w0.y;
            a2 += cA.y * w1.x + cB.y * w1.y;
            a2 += cA.z * w2v.x + cB.z * w2v.y;
            a2 += cA.w * w3.x + cB.w * w3.y;
        }
        r = fmaxf(a2, 0.f) * fcw[tc];
    }
#pragma unroll
    for (int off = 16; off > 0; off >>= 1) r += __shfl_down(r, off);
    if (lane == 0) out[row] = r + fcb[0];
}

extern "C" void kernel_launch(void* const* d_in, const int* in_sizes, int n_in,
                              void* d_out, int out_size, void* d_ws, size_t ws_size,
                              hipStream_t stream) {
    const float* x   = (const float*)d_in[0];
    const int*   ei  = (const int*)d_in[1];
    const float* W1  = (const float*)d_in[2];
    const float* b1  = (const float*)d_in[3];
    const float* W2  = (const float*)d_in[4];
    const float* b2  = (const float*)d_in[5];
    const float* c1w = (const float*)d_in[6];
    const float* c1b = (const float*)d_in[7];
    const float* c2w = (const float*)d_in[8];
    const float* c2b = (const float*)d_in[9];
    const float* fcw = (const float*)d_in[10];
    const float* fcb = (const float*)d_in[11];
    float* out = (float*)d_out;

    const int E = in_sizes[1] / 2;
    const int* src = ei;
    const int* dst = ei + E;

    // ---- workspace layout (mA/mB now only N_NODES rows: 1.92M floats each) --
    const size_t SG = (size_t)N_NODES * RSTRIDE;
    int*    cnt      = (int*)d_ws;                 // 10240
    int*    row_ptr  = cnt + 10240;                // 10240
    int*    fill_pos = row_ptr + 10240;            // 10240
    int2*   edges    = (int2*)(fill_pos + 10240);  // E records
    float*  dinv     = (float*)(edges + E);        // 10240
    float4* w1p      = (float4*)(dinv + 10240);    // 2048 float4
    float2* w2p      = (float2*)(w1p + 2048);      // 1024 float2
    float*  mA       = (float*)(w2p + 1024);       // SG
    float*  mB       = mA + SG;                    // SG

    // ---- CSR build + weight packing ----
    hipMemsetAsync(cnt, 0, N_NODES * sizeof(int), stream);
    hist_kernel<<<(E + 255) / 256, 256, 0, stream>>>(dst, cnt, E);
    scan_kernel<<<1, 1024, 0, stream>>>(cnt, row_ptr, fill_pos, dinv);
    fill_kernel<<<(E + 255) / 256, 256, 0, stream>>>(src, dst, dinv, fill_pos, edges, E);
    prep_kernel<<<12, 256, 0, stream>>>(c1w, c2w, w1p, w2p);

    // ---- graph path: rows < 10000 (2500 blocks each) ----
    gemm1_kernel <<<(N_NODES * HID) / 256, 256, 0, stream>>>(x, W1, mA);
    gatherA_kernel<<<(N_NODES * HID) / 256, 256, 0, stream>>>(mA, row_ptr, edges, dinv, b1, W2, mB);
    gatherBconv_kernel<<<(N_NODES * HID) / 256, 256, 0, stream>>>(mB, row_ptr, edges, dinv, b2,
                                                                  w1p, c1b, w2p, c2b, fcw, fcb, out);

    // ---- dense tail: rows >= 10000, fully fused (7500 blocks) ----
    fusedTail_kernel<<<((BN_TOT - N_NODES) * HID) / 256, 256, 0, stream>>>(
        x, W1, b1, W2, b2, w1p, c1b, w2p, c2b, fcw, fcb, out);
}

// Round 12
// 175.648 us; speedup vs baseline: 1.4500x; 1.4500x over previous
//
#include <hip/hip_runtime.h>

#define N_NODES 10000
#define BN_TOT  40000
#define HID     64
#define IN_F    16
#define TCH     32
#define NW      12
#define RSTRIDE 192   // floats per row: planes [t=3][ch=64] at +0B, +256B, +512B

// ---------------- histogram of dst (degree = cnt + 1) ------------------------
__global__ void hist_kernel(const int* __restrict__ dst, int* __restrict__ cnt, int E) {
    int e = blockIdx.x * blockDim.x + threadIdx.x;
    if (e < E) atomicAdd(&cnt[dst[e]], 1);
}

// ---------------- single-block exclusive scan over 10000 bins ----------------
__global__ __launch_bounds__(1024) void scan_kernel(const int* __restrict__ cnt,
                                                    int* __restrict__ row_ptr,
                                                    int* __restrict__ fill_pos,
                                                    float* __restrict__ dinv) {
    __shared__ int part[1024];
    int t = threadIdx.x;
    int base = t * 10;
    int s = 0;
#pragma unroll
    for (int k = 0; k < 10; ++k) {
        int b = base + k;
        if (b < N_NODES) s += cnt[b];
    }
    part[t] = s;
    __syncthreads();
    for (int off = 1; off < 1024; off <<= 1) {
        int v = 0;
        if (t >= off) v = part[t - off];
        __syncthreads();
        part[t] += v;
        __syncthreads();
    }
    int running = (t == 0) ? 0 : part[t - 1];
#pragma unroll
    for (int k = 0; k < 10; ++k) {
        int b = base + k;
        if (b < N_NODES) {
            row_ptr[b]  = running;
            fill_pos[b] = running;
            int c = cnt[b];
            dinv[b] = rsqrtf((float)c + 1.0f);
            running += c;
        }
    }
    if (t == 1023) row_ptr[N_NODES] = part[1023];
}

// ---------------- CSR bucket fill: edge record = {src byte offset, ne} -------
__global__ void fill_kernel(const int* __restrict__ src, const int* __restrict__ dst,
                            const float* __restrict__ dinv,
                            int* __restrict__ fill_pos,
                            int2* __restrict__ edges, int E) {
    int e = blockIdx.x * blockDim.x + threadIdx.x;
    if (e >= E) return;
    int s = src[e], d = dst[e];
    int pos = atomicAdd(&fill_pos[d], 1);
    edges[pos] = make_int2(s * (RSTRIDE * 4), __float_as_int(dinv[s] * dinv[d]));
}

// ---------------- pack conv weights: float4 / float2 per (ic, tc) ------------
__global__ void prep_kernel(const float* __restrict__ c1w, const float* __restrict__ c2w,
                            float4* __restrict__ w1p, float2* __restrict__ w2p) {
    int idx = blockIdx.x * blockDim.x + threadIdx.x;   // 3072 threads
    if (idx < 2048) {
        int tc = idx & 31, ic = idx >> 5;
        const float* p = c1w + tc * 192 + ic * 3;
        w1p[idx] = make_float4(p[0], p[1], p[2], 0.f);
    } else {
        int i2 = idx - 2048;
        int tc = i2 & 31, ic = i2 >> 5;
        const float* p = c2w + tc * 96 + ic * 3;
        w2p[i2] = make_float2(p[0], p[1]);
    }
}

// ---------------- GEMM1 (rows < N_NODES): m[n][t][64] = x @ W1 ---------------
__global__ __launch_bounds__(256) void gemm1_kernel(const float* __restrict__ x,
                                                    const float* __restrict__ W1,
                                                    float* __restrict__ m) {
    int idx = blockIdx.x * blockDim.x + threadIdx.x;   // 640,000 threads
    int oc = idx & 63;
    int n = __builtin_amdgcn_readfirstlane(idx >> 6);  // row < 10000, b = 0
    const float* xb = x + (size_t)n * IN_F;
    float s0 = 0.f, s1 = 0.f, s2 = 0.f;
#pragma unroll
    for (int f = 0; f < IN_F; ++f) {
        float wv = W1[f * HID + oc];
        s0 += xb[(size_t)9  * N_NODES * IN_F + f] * wv;
        s1 += xb[(size_t)10 * N_NODES * IN_F + f] * wv;
        s2 += xb[(size_t)11 * N_NODES * IN_F + f] * wv;
    }
    float* mr = m + (size_t)n * RSTRIDE;
    mr[oc] = s0; mr[64 + oc] = s1; mr[128 + oc] = s2;
}

// ---- gatherA (rows < N_NODES): h1 = relu(agg+self+b1); m2 = h1 @ W2 ---------
// W2 (16 KB) is L1-resident — this epilogue never thrashed.
__global__ __launch_bounds__(256, 8) void gatherA_kernel(
        const float* __restrict__ m, const int* __restrict__ row_ptr,
        const int2* __restrict__ edges,
        const float* __restrict__ dinv, const float* __restrict__ b1,
        const float* __restrict__ W2, float* __restrict__ m2) {
    __shared__ float hs[4][3][HID];
    int gid = blockIdx.x * blockDim.x + threadIdx.x;   // 10000 waves
    int lane = threadIdx.x & 63;
    int wv = threadIdx.x >> 6;
    int row = __builtin_amdgcn_readfirstlane(gid >> 6);
    const int lo0 = lane * 4, lo1 = 256 + lane * 4, lo2 = 512 + lane * 4;
    const char* mrow = (const char*)m + (size_t)row * (RSTRIDE * 4);
    float dv = dinv[row];
    float sn = dv * dv;
    float s0 = sn * *(const float*)(mrow + lo0);
    float s1 = sn * *(const float*)(mrow + lo1);
    float s2 = sn * *(const float*)(mrow + lo2);
    int j = row_ptr[row], end = row_ptr[row + 1];
    for (; j + 3 < end; j += 4) {
        int2 e0 = edges[j], e1 = edges[j + 1], e2 = edges[j + 2], e3 = edges[j + 3];
        const char* q0 = (const char*)m + e0.x;
        const char* q1 = (const char*)m + e1.x;
        const char* q2 = (const char*)m + e2.x;
        const char* q3 = (const char*)m + e3.x;
        float w0 = __int_as_float(e0.y), w1 = __int_as_float(e1.y);
        float w2 = __int_as_float(e2.y), w3 = __int_as_float(e3.y);
        s0 += w0 * *(const float*)(q0 + lo0) + w1 * *(const float*)(q1 + lo0)
            + w2 * *(const float*)(q2 + lo0) + w3 * *(const float*)(q3 + lo0);
        s1 += w0 * *(const float*)(q0 + lo1) + w1 * *(const float*)(q1 + lo1)
            + w2 * *(const float*)(q2 + lo1) + w3 * *(const float*)(q3 + lo1);
        s2 += w0 * *(const float*)(q0 + lo2) + w1 * *(const float*)(q1 + lo2)
            + w2 * *(const float*)(q2 + lo2) + w3 * *(const float*)(q3 + lo2);
    }
    for (; j < end; ++j) {
        int2 e = edges[j];
        const char* q = (const char*)m + e.x;
        float w = __int_as_float(e.y);
        s0 += w * *(const float*)(q + lo0);
        s1 += w * *(const float*)(q + lo1);
        s2 += w * *(const float*)(q + lo2);
    }
    float bb = b1[lane];
    hs[wv][0][lane] = fmaxf(s0 + bb, 0.f);
    hs[wv][1][lane] = fmaxf(s1 + bb, 0.f);
    hs[wv][2][lane] = fmaxf(s2 + bb, 0.f);
    __builtin_amdgcn_wave_barrier();
    const float4* h0v = (const float4*)&hs[wv][0][0];
    const float4* h1v = (const float4*)&hs[wv][1][0];
    const float4* h2v = (const float4*)&hs[wv][2][0];
    float t0 = 0.f, t1 = 0.f, t2 = 0.f;
#pragma unroll
    for (int ic4 = 0; ic4 < 16; ++ic4) {
        float4 h0 = h0v[ic4], h1 = h1v[ic4], h2 = h2v[ic4];
        float wA = W2[(ic4 * 4 + 0) * HID + lane];
        float wB = W2[(ic4 * 4 + 1) * HID + lane];
        float wC = W2[(ic4 * 4 + 2) * HID + lane];
        float wD = W2[(ic4 * 4 + 3) * HID + lane];
        t0 += h0.x * wA + h0.y * wB + h0.z * wC + h0.w * wD;
        t1 += h1.x * wA + h1.y * wB + h1.z * wC + h1.w * wD;
        t2 += h2.x * wA + h2.y * wB + h2.z * wC + h2.w * wD;
    }
    float* m2r = m2 + (size_t)row * RSTRIDE;
    m2r[lane] = t0; m2r[64 + lane] = t1; m2r[128 + lane] = t2;
}

// ---- gatherB (rows < N_NODES), LEAN: H = relu(agg+self+b2), no conv ---------
__global__ __launch_bounds__(256, 8) void gatherB_kernel(
        const float* __restrict__ m, const int* __restrict__ row_ptr,
        const int2* __restrict__ edges,
        const float* __restrict__ dinv, const float* __restrict__ b2,
        float* __restrict__ Hout) {
    int gid = blockIdx.x * blockDim.x + threadIdx.x;   // 10000 waves
    int lane = threadIdx.x & 63;
    int row = __builtin_amdgcn_readfirstlane(gid >> 6);
    const int lo0 = lane * 4, lo1 = 256 + lane * 4, lo2 = 512 + lane * 4;
    const char* mrow = (const char*)m + (size_t)row * (RSTRIDE * 4);
    float dv = dinv[row];
    float sn = dv * dv;
    float s0 = sn * *(const float*)(mrow + lo0);
    float s1 = sn * *(const float*)(mrow + lo1);
    float s2 = sn * *(const float*)(mrow + lo2);
    int j = row_ptr[row], end = row_ptr[row + 1];
    for (; j + 3 < end; j += 4) {
        int2 e0 = edges[j], e1 = edges[j + 1], e2 = edges[j + 2], e3 = edges[j + 3];
        const char* q0 = (const char*)m + e0.x;
        const char* q1 = (const char*)m + e1.x;
        const char* q2 = (const char*)m + e2.x;
        const char* q3 = (const char*)m + e3.x;
        float w0 = __int_as_float(e0.y), w1 = __int_as_float(e1.y);
        float w2 = __int_as_float(e2.y), w3 = __int_as_float(e3.y);
        s0 += w0 * *(const float*)(q0 + lo0) + w1 * *(const float*)(q1 + lo0)
            + w2 * *(const float*)(q2 + lo0) + w3 * *(const float*)(q3 + lo0);
        s1 += w0 * *(const float*)(q0 + lo1) + w1 * *(const float*)(q1 + lo1)
            + w2 * *(const float*)(q2 + lo1) + w3 * *(const float*)(q3 + lo1);
        s2 += w0 * *(const float*)(q0 + lo2) + w1 * *(const float*)(q1 + lo2)
            + w2 * *(const float*)(q2 + lo2) + w3 * *(const float*)(q3 + lo2);
    }
    for (; j < end; ++j) {
        int2 e = edges[j];
        const char* q = (const char*)m + e.x;
        float w = __int_as_float(e.y);
        s0 += w * *(const float*)(q + lo0);
        s1 += w * *(const float*)(q + lo1);
        s2 += w * *(const float*)(q + lo2);
    }
    float bb = b2[lane];
    float* Hr = Hout + (size_t)row * RSTRIDE;
    Hr[lane]       = fmaxf(s0 + bb, 0.f);
    Hr[64 + lane]  = fmaxf(s1 + bb, 0.f);
    Hr[128 + lane] = fmaxf(s2 + bb, 0.f);
}

// ---- convfc: ALL 40000 rows, 4 rows/wave. Graph rows read H; dense rows -----
// compute gemm1+W2 inline. conv1 weights (32 KB) staged in LDS per block;
// remaining VMEM weight set (W1+W2+w2p ~28 KB) fits L1.
__global__ __launch_bounds__(256, 4) void convfc_kernel(
        const float* __restrict__ H, const float* __restrict__ x,
        const float* __restrict__ W1, const float* __restrict__ b1,
        const float* __restrict__ W2, const float* __restrict__ b2,
        const float4* __restrict__ w1p, const float* __restrict__ b1c,
        const float2* __restrict__ w2p, const float* __restrict__ b2c,
        const float* __restrict__ fcw, const float* __restrict__ fcb,
        float* __restrict__ out) {
    __shared__ float4 w1s[2048];            // 32 KB conv1 weights
    __shared__ float  hs[4][4][4][HID];     // [wave][row][plane 0..2=t, 3=zero][ch]
    __shared__ float  c1s[4][4][2][TCH];    // [wave][row][t10/t11][tc]
    int t = threadIdx.x;
#pragma unroll
    for (int i = 0; i < 8; ++i) w1s[i * 256 + t] = w1p[i * 256 + t];
    __syncthreads();

    int wv = t >> 6, lane = t & 63;
    int r0 = __builtin_amdgcn_readfirstlane((blockIdx.x * 4 + wv) * 4);  // 4 rows/wave

    if (r0 < N_NODES) {
        // graph rows: H already final (gather+relu+b2 done)
#pragma unroll
        for (int r = 0; r < 4; ++r) {
            const float* Hr = H + (size_t)(r0 + r) * RSTRIDE;
            hs[wv][r][0][lane] = Hr[lane];
            hs[wv][r][1][lane] = Hr[64 + lane];
            hs[wv][r][2][lane] = Hr[128 + lane];
        }
    } else {
        // dense rows: deg=1, agg=0 -> full chain from x
        int b = r0 / N_NODES;
        int n0 = r0 - b * N_NODES;
        float w1r[16];
#pragma unroll
        for (int f = 0; f < IN_F; ++f) w1r[f] = W1[f * HID + lane];
        float s[12];
#pragma unroll
        for (int r = 0; r < 4; ++r) {
#pragma unroll
            for (int tt = 0; tt < 3; ++tt) {
                const float* xp = x + ((size_t)(b * NW + 9 + tt) * N_NODES + (n0 + r)) * IN_F;
                float a = 0.f;
#pragma unroll
                for (int f = 0; f < IN_F; ++f) a += xp[f] * w1r[f];  // xp uniform -> s_loads
                s[r * 3 + tt] = a;
            }
        }
        float bb1 = b1[lane];
#pragma unroll
        for (int r = 0; r < 4; ++r) {
            hs[wv][r][0][lane] = fmaxf(s[r * 3 + 0] + bb1, 0.f);
            hs[wv][r][1][lane] = fmaxf(s[r * 3 + 1] + bb1, 0.f);
            hs[wv][r][2][lane] = fmaxf(s[r * 3 + 2] + bb1, 0.f);
        }
        __builtin_amdgcn_wave_barrier();
        float acc[12];
#pragma unroll
        for (int mm = 0; mm < 12; ++mm) acc[mm] = 0.f;
#pragma unroll
        for (int k4 = 0; k4 < 16; ++k4) {
            float wA = W2[(k4 * 4 + 0) * HID + lane];
            float wB = W2[(k4 * 4 + 1) * HID + lane];
            float wC = W2[(k4 * 4 + 2) * HID + lane];
            float wD = W2[(k4 * 4 + 3) * HID + lane];
#pragma unroll
            for (int r = 0; r < 4; ++r) {
#pragma unroll
                for (int tt = 0; tt < 3; ++tt) {
                    float4 h = ((const float4*)&hs[wv][r][tt][0])[k4];  // broadcast
                    acc[r * 3 + tt] += h.x * wA + h.y * wB + h.z * wC + h.w * wD;
                }
            }
        }
        __builtin_amdgcn_wave_barrier();
        float bb2 = b2[lane];
#pragma unroll
        for (int r = 0; r < 4; ++r) {
            hs[wv][r][0][lane] = fmaxf(acc[r * 3 + 0] + bb2, 0.f);
            hs[wv][r][1][lane] = fmaxf(acc[r * 3 + 1] + bb2, 0.f);
            hs[wv][r][2][lane] = fmaxf(acc[r * 3 + 2] + bb2, 0.f);
        }
    }
#pragma unroll
    for (int r = 0; r < 4; ++r) hs[wv][r][3][lane] = 0.f;  // pad plane
    __builtin_amdgcn_wave_barrier();

    // ---- conv1: lane (pos,tc) computes c1[10+pos][tc] for 4 rows ----
    int pos = lane >> 5, tc = lane & 31;
    int pA = pos, pB = pos + 1, pC = (pos == 0) ? 2 : 3;  // taps H[9+pos+k], pad->zeros
    float a1[4];
    float bc1 = b1c[tc];
#pragma unroll
    for (int r = 0; r < 4; ++r) a1[r] = bc1;
#pragma unroll
    for (int ic4 = 0; ic4 < 16; ++ic4) {
        float4 wa = w1s[(ic4 * 4 + 0) * 32 + tc];
        float4 wb = w1s[(ic4 * 4 + 1) * 32 + tc];
        float4 wc = w1s[(ic4 * 4 + 2) * 32 + tc];
        float4 wd = w1s[(ic4 * 4 + 3) * 32 + tc];
#pragma unroll
        for (int r = 0; r < 4; ++r) {
            float4 hA = ((const float4*)&hs[wv][r][pA][0])[ic4];
            float4 hB = ((const float4*)&hs[wv][r][pB][0])[ic4];
            float4 hC = ((const float4*)&hs[wv][r][pC][0])[ic4];
            a1[r] += hA.x * wa.x + hB.x * wa.y + hC.x * wa.z
                   + hA.y * wb.x + hB.y * wb.y + hC.y * wb.z
                   + hA.z * wc.x + hB.z * wc.y + hC.z * wc.z
                   + hA.w * wd.x + hB.w * wd.y + hC.w * wd.z;
        }
    }
#pragma unroll
    for (int r = 0; r < 4; ++r) c1s[wv][r][pos][tc] = fmaxf(a1[r], 0.f);
    __builtin_amdgcn_wave_barrier();

    // ---- conv2 @ t=11 + relu + fc: half-wave pos handles rows {2pos, 2pos+1} ----
    int rr = pos * 2;
    float bc2 = b2c[tc];
    float a2q0 = bc2, a2q1 = bc2;
#pragma unroll
    for (int ic4 = 0; ic4 < 8; ++ic4) {
        float2 w0 = w2p[(ic4 * 4 + 0) * 32 + tc];
        float2 w1 = w2p[(ic4 * 4 + 1) * 32 + tc];
        float2 w2v = w2p[(ic4 * 4 + 2) * 32 + tc];
        float2 w3 = w2p[(ic4 * 4 + 3) * 32 + tc];
        float4 cA0 = ((const float4*)&c1s[wv][rr + 0][0][0])[ic4];
        float4 cB0 = ((const float4*)&c1s[wv][rr + 0][1][0])[ic4];
        float4 cA1 = ((const float4*)&c1s[wv][rr + 1][0][0])[ic4];
        float4 cB1 = ((const float4*)&c1s[wv][rr + 1][1][0])[ic4];
        a2q0 += cA0.x * w0.x + cB0.x * w0.y + cA0.y * w1.x + cB0.y * w1.y
              + cA0.z * w2v.x + cB0.z * w2v.y + cA0.w * w3.x + cB0.w * w3.y;
        a2q1 += cA1.x * w0.x + cB1.x * w0.y + cA1.y * w1.x + cB1.y * w1.y
              + cA1.z * w2v.x + cB1.z * w2v.y + cA1.w * w3.x + cB1.w * w3.y;
    }
    float fw = fcw[tc];
    float r0v = fmaxf(a2q0, 0.f) * fw;
    float r1v = fmaxf(a2q1, 0.f) * fw;
#pragma unroll
    for (int off = 16; off > 0; off >>= 1) {
        r0v += __shfl_down(r0v, off, 32);   // width-32: reduce within half-wave
        r1v += __shfl_down(r1v, off, 32);
    }
    if (tc == 0) {
        float fb = fcb[0];
        out[r0 + rr + 0] = r0v + fb;
        out[r0 + rr + 1] = r1v + fb;
    }
}

extern "C" void kernel_launch(void* const* d_in, const int* in_sizes, int n_in,
                              void* d_out, int out_size, void* d_ws, size_t ws_size,
                              hipStream_t stream) {
    const float* x   = (const float*)d_in[0];
    const int*   ei  = (const int*)d_in[1];
    const float* W1  = (const float*)d_in[2];
    const float* b1  = (const float*)d_in[3];
    const float* W2  = (const float*)d_in[4];
    const float* b2  = (const float*)d_in[5];
    const float* c1w = (const float*)d_in[6];
    const float* c1b = (const float*)d_in[7];
    const float* c2w = (const float*)d_in[8];
    const float* c2b = (const float*)d_in[9];
    const float* fcw = (const float*)d_in[10];
    const float* fcb = (const float*)d_in[11];
    float* out = (float*)d_out;

    const int E = in_sizes[1] / 2;
    const int* src = ei;
    const int* dst = ei + E;

    // ---- workspace layout (graph arrays: N_NODES rows only, 7.7 MB each) ----
    const size_t SG = (size_t)N_NODES * RSTRIDE;
    int*    cnt      = (int*)d_ws;                 // 10240
    int*    row_ptr  = cnt + 10240;                // 10240
    int*    fill_pos = row_ptr + 10240;            // 10240
    int2*   edges    = (int2*)(fill_pos + 10240);  // E records
    float*  dinv     = (float*)(edges + E);        // 10240
    float4* w1p      = (float4*)(dinv + 10240);    // 2048 float4 (16B-aligned)
    float2* w2p      = (float2*)(w1p + 2048);      // 1024 float2
    float*  mA       = (float*)(w2p + 1024);       // SG
    float*  mB       = mA + SG;                    // SG
    float*  Hb       = mB + SG;                    // SG

    // ---- CSR build + weight packing ----
    hipMemsetAsync(cnt, 0, N_NODES * sizeof(int), stream);
    hist_kernel<<<(E + 255) / 256, 256, 0, stream>>>(dst, cnt, E);
    scan_kernel<<<1, 1024, 0, stream>>>(cnt, row_ptr, fill_pos, dinv);
    fill_kernel<<<(E + 255) / 256, 256, 0, stream>>>(src, dst, dinv, fill_pos, edges, E);
    prep_kernel<<<12, 256, 0, stream>>>(c1w, c2w, w1p, w2p);

    // ---- graph path: rows < 10000 ----
    gemm1_kernel <<<(N_NODES * HID) / 256, 256, 0, stream>>>(x, W1, mA);
    gatherA_kernel<<<(N_NODES * HID) / 256, 256, 0, stream>>>(mA, row_ptr, edges, dinv, b1, W2, mB);
    gatherB_kernel<<<(N_NODES * HID) / 256, 256, 0, stream>>>(mB, row_ptr, edges, dinv, b2, Hb);

    // ---- conv+fc for ALL rows (graph rows read Hb; dense rows from x) ----
    convfc_kernel<<<BN_TOT / 16, 256, 0, stream>>>(Hb, x, W1, b1, W2, b2,
                                                   w1p, c1b, w2p, c2b, fcw, fcb, out);
}

// Round 13
// 170.524 us; speedup vs baseline: 1.4936x; 1.0300x over previous
//
#include <hip/hip_runtime.h>

#define N_NODES 10000
#define BN_TOT  40000
#define HID     64
#define IN_F    16
#define TCH     32
#define NW      12
#define RSTRIDE 192   // floats per row: planes [t=3][ch=64] at +0B, +256B, +512B

// ---------------- histogram of dst (degree = cnt + 1) ------------------------
__global__ void hist_kernel(const int* __restrict__ dst, int* __restrict__ cnt, int E) {
    int e = blockIdx.x * blockDim.x + threadIdx.x;
    if (e < E) atomicAdd(&cnt[dst[e]], 1);
}

// ---------------- single-block exclusive scan over 10000 bins ----------------
__global__ __launch_bounds__(1024) void scan_kernel(const int* __restrict__ cnt,
                                                    int* __restrict__ row_ptr,
                                                    int* __restrict__ fill_pos,
                                                    float* __restrict__ dinv) {
    __shared__ int part[1024];
    int t = threadIdx.x;
    int base = t * 10;
    int s = 0;
#pragma unroll
    for (int k = 0; k < 10; ++k) {
        int b = base + k;
        if (b < N_NODES) s += cnt[b];
    }
    part[t] = s;
    __syncthreads();
    for (int off = 1; off < 1024; off <<= 1) {
        int v = 0;
        if (t >= off) v = part[t - off];
        __syncthreads();
        part[t] += v;
        __syncthreads();
    }
    int running = (t == 0) ? 0 : part[t - 1];
#pragma unroll
    for (int k = 0; k < 10; ++k) {
        int b = base + k;
        if (b < N_NODES) {
            row_ptr[b]  = running;
            fill_pos[b] = running;
            int c = cnt[b];
            dinv[b] = rsqrtf((float)c + 1.0f);
            running += c;
        }
    }
    if (t == 1023) row_ptr[N_NODES] = part[1023];
}

// ---------------- CSR bucket fill: edge record = {src byte offset, ne} -------
__global__ void fill_kernel(const int* __restrict__ src, const int* __restrict__ dst,
                            const float* __restrict__ dinv,
                            int* __restrict__ fill_pos,
                            int2* __restrict__ edges, int E) {
    int e = blockIdx.x * blockDim.x + threadIdx.x;
    if (e >= E) return;
    int s = src[e], d = dst[e];
    int pos = atomicAdd(&fill_pos[d], 1);
    edges[pos] = make_int2(s * (RSTRIDE * 4), __float_as_int(dinv[s] * dinv[d]));
}

// ---------------- pack conv weights: float4 / float2 per (ic, tc) ------------
__global__ void prep_kernel(const float* __restrict__ c1w, const float* __restrict__ c2w,
                            float4* __restrict__ w1p, float2* __restrict__ w2p) {
    int idx = blockIdx.x * blockDim.x + threadIdx.x;   // 3072 threads
    if (idx < 2048) {
        int tc = idx & 31, ic = idx >> 5;
        const float* p = c1w + tc * 192 + ic * 3;
        w1p[idx] = make_float4(p[0], p[1], p[2], 0.f);
    } else {
        int i2 = idx - 2048;
        int tc = i2 & 31, ic = i2 >> 5;
        const float* p = c2w + tc * 96 + ic * 3;
        w2p[i2] = make_float2(p[0], p[1]);
    }
}

// ---------------- GEMM1 (rows < N_NODES): m[n][t][64] = x @ W1 ---------------
__global__ __launch_bounds__(256) void gemm1_kernel(const float* __restrict__ x,
                                                    const float* __restrict__ W1,
                                                    float* __restrict__ m) {
    int idx = blockIdx.x * blockDim.x + threadIdx.x;   // 640,000 threads
    int oc = idx & 63;
    int n = __builtin_amdgcn_readfirstlane(idx >> 6);  // row < 10000, b = 0
    const float* xb = x + (size_t)n * IN_F;
    float s0 = 0.f, s1 = 0.f, s2 = 0.f;
#pragma unroll
    for (int f = 0; f < IN_F; ++f) {
        float wv = W1[f * HID + oc];
        s0 += xb[(size_t)9  * N_NODES * IN_F + f] * wv;
        s1 += xb[(size_t)10 * N_NODES * IN_F + f] * wv;
        s2 += xb[(size_t)11 * N_NODES * IN_F + f] * wv;
    }
    float* mr = m + (size_t)n * RSTRIDE;
    mr[oc] = s0; mr[64 + oc] = s1; mr[128 + oc] = s2;
}

// ---- gatherA (rows < N_NODES): h1 = relu(agg+self+b1); m2 = h1 @ W2 ---------
__global__ __launch_bounds__(256, 8) void gatherA_kernel(
        const float* __restrict__ m, const int* __restrict__ row_ptr,
        const int2* __restrict__ edges,
        const float* __restrict__ dinv, const float* __restrict__ b1,
        const float* __restrict__ W2, float* __restrict__ m2) {
    __shared__ float hs[4][3][HID];
    int gid = blockIdx.x * blockDim.x + threadIdx.x;   // 10000 waves
    int lane = threadIdx.x & 63;
    int wv = threadIdx.x >> 6;
    int row = __builtin_amdgcn_readfirstlane(gid >> 6);
    const int lo0 = lane * 4, lo1 = 256 + lane * 4, lo2 = 512 + lane * 4;
    const char* mrow = (const char*)m + (size_t)row * (RSTRIDE * 4);
    float dv = dinv[row];
    float sn = dv * dv;
    float s0 = sn * *(const float*)(mrow + lo0);
    float s1 = sn * *(const float*)(mrow + lo1);
    float s2 = sn * *(const float*)(mrow + lo2);
    int j = row_ptr[row], end = row_ptr[row + 1];
    for (; j + 3 < end; j += 4) {
        int2 e0 = edges[j], e1 = edges[j + 1], e2 = edges[j + 2], e3 = edges[j + 3];
        const char* q0 = (const char*)m + e0.x;
        const char* q1 = (const char*)m + e1.x;
        const char* q2 = (const char*)m + e2.x;
        const char* q3 = (const char*)m + e3.x;
        float w0 = __int_as_float(e0.y), w1 = __int_as_float(e1.y);
        float w2 = __int_as_float(e2.y), w3 = __int_as_float(e3.y);
        s0 += w0 * *(const float*)(q0 + lo0) + w1 * *(const float*)(q1 + lo0)
            + w2 * *(const float*)(q2 + lo0) + w3 * *(const float*)(q3 + lo0);
        s1 += w0 * *(const float*)(q0 + lo1) + w1 * *(const float*)(q1 + lo1)
            + w2 * *(const float*)(q2 + lo1) + w3 * *(const float*)(q3 + lo1);
        s2 += w0 * *(const float*)(q0 + lo2) + w1 * *(const float*)(q1 + lo2)
            + w2 * *(const float*)(q2 + lo2) + w3 * *(const float*)(q3 + lo2);
    }
    for (; j < end; ++j) {
        int2 e = edges[j];
        const char* q = (const char*)m + e.x;
        float w = __int_as_float(e.y);
        s0 += w * *(const float*)(q + lo0);
        s1 += w * *(const float*)(q + lo1);
        s2 += w * *(const float*)(q + lo2);
    }
    float bb = b1[lane];
    hs[wv][0][lane] = fmaxf(s0 + bb, 0.f);
    hs[wv][1][lane] = fmaxf(s1 + bb, 0.f);
    hs[wv][2][lane] = fmaxf(s2 + bb, 0.f);
    __builtin_amdgcn_wave_barrier();
    const float4* h0v = (const float4*)&hs[wv][0][0];
    const float4* h1v = (const float4*)&hs[wv][1][0];
    const float4* h2v = (const float4*)&hs[wv][2][0];
    float t0 = 0.f, t1 = 0.f, t2 = 0.f;
#pragma unroll
    for (int ic4 = 0; ic4 < 16; ++ic4) {
        float4 h0 = h0v[ic4], h1 = h1v[ic4], h2 = h2v[ic4];
        float wA = W2[(ic4 * 4 + 0) * HID + lane];
        float wB = W2[(ic4 * 4 + 1) * HID + lane];
        float wC = W2[(ic4 * 4 + 2) * HID + lane];
        float wD = W2[(ic4 * 4 + 3) * HID + lane];
        t0 += h0.x * wA + h0.y * wB + h0.z * wC + h0.w * wD;
        t1 += h1.x * wA + h1.y * wB + h1.z * wC + h1.w * wD;
        t2 += h2.x * wA + h2.y * wB + h2.z * wC + h2.w * wD;
    }
    float* m2r = m2 + (size_t)row * RSTRIDE;
    m2r[lane] = t0; m2r[64 + lane] = t1; m2r[128 + lane] = t2;
}

// ---- gatherB (rows < N_NODES), LEAN: H = relu(agg+self+b2), no conv ---------
__global__ __launch_bounds__(256, 8) void gatherB_kernel(
        const float* __restrict__ m, const int* __restrict__ row_ptr,
        const int2* __restrict__ edges,
        const float* __restrict__ dinv, const float* __restrict__ b2,
        float* __restrict__ Hout) {
    int gid = blockIdx.x * blockDim.x + threadIdx.x;   // 10000 waves
    int lane = threadIdx.x & 63;
    int row = __builtin_amdgcn_readfirstlane(gid >> 6);
    const int lo0 = lane * 4, lo1 = 256 + lane * 4, lo2 = 512 + lane * 4;
    const char* mrow = (const char*)m + (size_t)row * (RSTRIDE * 4);
    float dv = dinv[row];
    float sn = dv * dv;
    float s0 = sn * *(const float*)(mrow + lo0);
    float s1 = sn * *(const float*)(mrow + lo1);
    float s2 = sn * *(const float*)(mrow + lo2);
    int j = row_ptr[row], end = row_ptr[row + 1];
    for (; j + 3 < end; j += 4) {
        int2 e0 = edges[j], e1 = edges[j + 1], e2 = edges[j + 2], e3 = edges[j + 3];
        const char* q0 = (const char*)m + e0.x;
        const char* q1 = (const char*)m + e1.x;
        const char* q2 = (const char*)m + e2.x;
        const char* q3 = (const char*)m + e3.x;
        float w0 = __int_as_float(e0.y), w1 = __int_as_float(e1.y);
        float w2 = __int_as_float(e2.y), w3 = __int_as_float(e3.y);
        s0 += w0 * *(const float*)(q0 + lo0) + w1 * *(const float*)(q1 + lo0)
            + w2 * *(const float*)(q2 + lo0) + w3 * *(const float*)(q3 + lo0);
        s1 += w0 * *(const float*)(q0 + lo1) + w1 * *(const float*)(q1 + lo1)
            + w2 * *(const float*)(q2 + lo1) + w3 * *(const float*)(q3 + lo1);
        s2 += w0 * *(const float*)(q0 + lo2) + w1 * *(const float*)(q1 + lo2)
            + w2 * *(const float*)(q2 + lo2) + w3 * *(const float*)(q3 + lo2);
    }
    for (; j < end; ++j) {
        int2 e = edges[j];
        const char* q = (const char*)m + e.x;
        float w = __int_as_float(e.y);
        s0 += w * *(const float*)(q + lo0);
        s1 += w * *(const float*)(q + lo1);
        s2 += w * *(const float*)(q + lo2);
    }
    float bb = b2[lane];
    float* Hr = Hout + (size_t)row * RSTRIDE;
    Hr[lane]       = fmaxf(s0 + bb, 0.f);
    Hr[64 + lane]  = fmaxf(s1 + bb, 0.f);
    Hr[128 + lane] = fmaxf(s2 + bb, 0.f);
}

// ---- convfc: ALL 40000 rows, 512-thread blocks, 8 waves x 4 rows/wave. ------
// conv1 weights (32 KB) staged once per block into LDS, amortized over 8 waves.
// LDS = 32K (w1s) + 24K (hs) + 8K (c1s) = 64 KB -> 2 blocks/CU = 16 waves/CU.
// Pad tap handled by scaling k=2 weights with (pos==0) instead of a zero plane.
__global__ __launch_bounds__(512, 4) void convfc_kernel(
        const float* __restrict__ H, const float* __restrict__ x,
        const float* __restrict__ W1, const float* __restrict__ b1,
        const float* __restrict__ W2, const float* __restrict__ b2,
        const float4* __restrict__ w1p, const float* __restrict__ b1c,
        const float2* __restrict__ w2p, const float* __restrict__ b2c,
        const float* __restrict__ fcw, const float* __restrict__ fcb,
        float* __restrict__ out) {
    __shared__ float4 w1s[2048];            // 32 KB conv1 weights
    __shared__ float  hs[8][4][3][HID];     // [wave][row][t-plane][ch]  24 KB
    __shared__ float  c1s[8][4][2][TCH];    // [wave][row][t10/t11][tc]   8 KB
    int t = threadIdx.x;
#pragma unroll
    for (int i = 0; i < 4; ++i) w1s[i * 512 + t] = w1p[i * 512 + t];
    __syncthreads();

    int wv = t >> 6, lane = t & 63;
    int r0 = __builtin_amdgcn_readfirstlane((blockIdx.x * 8 + wv) * 4);  // 4 rows/wave

    if (r0 < N_NODES) {
        // graph rows: H already final (gather+relu+b2 done)
#pragma unroll
        for (int r = 0; r < 4; ++r) {
            const float* Hr = H + (size_t)(r0 + r) * RSTRIDE;
            hs[wv][r][0][lane] = Hr[lane];
            hs[wv][r][1][lane] = Hr[64 + lane];
            hs[wv][r][2][lane] = Hr[128 + lane];
        }
    } else {
        // dense rows: deg=1, agg=0 -> full chain from x
        int b = r0 / N_NODES;
        int n0 = r0 - b * N_NODES;
        float w1r[16];
#pragma unroll
        for (int f = 0; f < IN_F; ++f) w1r[f] = W1[f * HID + lane];
        float s[12];
#pragma unroll
        for (int r = 0; r < 4; ++r) {
#pragma unroll
            for (int tt = 0; tt < 3; ++tt) {
                const float* xp = x + ((size_t)(b * NW + 9 + tt) * N_NODES + (n0 + r)) * IN_F;
                float a = 0.f;
#pragma unroll
                for (int f = 0; f < IN_F; ++f) a += xp[f] * w1r[f];  // xp uniform -> s_loads
                s[r * 3 + tt] = a;
            }
        }
        float bb1 = b1[lane];
#pragma unroll
        for (int r = 0; r < 4; ++r) {
            hs[wv][r][0][lane] = fmaxf(s[r * 3 + 0] + bb1, 0.f);
            hs[wv][r][1][lane] = fmaxf(s[r * 3 + 1] + bb1, 0.f);
            hs[wv][r][2][lane] = fmaxf(s[r * 3 + 2] + bb1, 0.f);
        }
        __builtin_amdgcn_wave_barrier();
        float acc[12];
#pragma unroll
        for (int mm = 0; mm < 12; ++mm) acc[mm] = 0.f;
#pragma unroll
        for (int k4 = 0; k4 < 16; ++k4) {
            float wA = W2[(k4 * 4 + 0) * HID + lane];
            float wB = W2[(k4 * 4 + 1) * HID + lane];
            float wC = W2[(k4 * 4 + 2) * HID + lane];
            float wD = W2[(k4 * 4 + 3) * HID + lane];
#pragma unroll
            for (int r = 0; r < 4; ++r) {
#pragma unroll
                for (int tt = 0; tt < 3; ++tt) {
                    float4 h = ((const float4*)&hs[wv][r][tt][0])[k4];  // broadcast
                    acc[r * 3 + tt] += h.x * wA + h.y * wB + h.z * wC + h.w * wD;
                }
            }
        }
        __builtin_amdgcn_wave_barrier();
        float bb2 = b2[lane];
#pragma unroll
        for (int r = 0; r < 4; ++r) {
            hs[wv][r][0][lane] = fmaxf(acc[r * 3 + 0] + bb2, 0.f);
            hs[wv][r][1][lane] = fmaxf(acc[r * 3 + 1] + bb2, 0.f);
            hs[wv][r][2][lane] = fmaxf(acc[r * 3 + 2] + bb2, 0.f);
        }
    }
    __builtin_amdgcn_wave_barrier();

    // ---- conv1: lane (pos,tc) computes c1[10+pos][tc] for 4 rows ----
    // taps: H[9+pos+k], k=0..2; k=2 at pos=1 is pad -> scale its weights to 0.
    int pos = lane >> 5, tc = lane & 31;
    int pA = pos, pB = pos + 1, pC = (pos == 0) ? 2 : 0;   // pC data irrelevant at pos=1
    float hCs = (pos == 0) ? 1.f : 0.f;
    float a1[4];
    float bc1 = b1c[tc];
#pragma unroll
    for (int r = 0; r < 4; ++r) a1[r] = bc1;
#pragma unroll
    for (int ic4 = 0; ic4 < 16; ++ic4) {
        float4 wa = w1s[(ic4 * 4 + 0) * 32 + tc];
        float4 wb = w1s[(ic4 * 4 + 1) * 32 + tc];
        float4 wc = w1s[(ic4 * 4 + 2) * 32 + tc];
        float4 wd = w1s[(ic4 * 4 + 3) * 32 + tc];
        float waz = wa.z * hCs, wbz = wb.z * hCs, wcz = wc.z * hCs, wdz = wd.z * hCs;
#pragma unroll
        for (int r = 0; r < 4; ++r) {
            float4 hA = ((const float4*)&hs[wv][r][pA][0])[ic4];
            float4 hB = ((const float4*)&hs[wv][r][pB][0])[ic4];
            float4 hC = ((const float4*)&hs[wv][r][pC][0])[ic4];
            a1[r] += hA.x * wa.x + hB.x * wa.y + hC.x * waz
                   + hA.y * wb.x + hB.y * wb.y + hC.y * wbz
                   + hA.z * wc.x + hB.z * wc.y + hC.z * wcz
                   + hA.w * wd.x + hB.w * wd.y + hC.w * wdz;
        }
    }
#pragma unroll
    for (int r = 0; r < 4; ++r) c1s[wv][r][pos][tc] = fmaxf(a1[r], 0.f);
    __builtin_amdgcn_wave_barrier();

    // ---- conv2 @ t=11 + relu + fc: half-wave pos handles rows {2pos, 2pos+1} ----
    int rr = pos * 2;
    float bc2 = b2c[tc];
    float a2q0 = bc2, a2q1 = bc2;
#pragma unroll
    for (int ic4 = 0; ic4 < 8; ++ic4) {
        float2 w0 = w2p[(ic4 * 4 + 0) * 32 + tc];
        float2 w1 = w2p[(ic4 * 4 + 1) * 32 + tc];
        float2 w2v = w2p[(ic4 * 4 + 2) * 32 + tc];
        float2 w3 = w2p[(ic4 * 4 + 3) * 32 + tc];
        float4 cA0 = ((const float4*)&c1s[wv][rr + 0][0][0])[ic4];
        float4 cB0 = ((const float4*)&c1s[wv][rr + 0][1][0])[ic4];
        float4 cA1 = ((const float4*)&c1s[wv][rr + 1][0][0])[ic4];
        float4 cB1 = ((const float4*)&c1s[wv][rr + 1][1][0])[ic4];
        a2q0 += cA0.x * w0.x + cB0.x * w0.y + cA0.y * w1.x + cB0.y * w1.y
              + cA0.z * w2v.x + cB0.z * w2v.y + cA0.w * w3.x + cB0.w * w3.y;
        a2q1 += cA1.x * w0.x + cB1.x * w0.y + cA1.y * w1.x + cB1.y * w1.y
              + cA1.z * w2v.x + cB1.z * w2v.y + cA1.w * w3.x + cB1.w * w3.y;
    }
    float fw = fcw[tc];
    float r0v = fmaxf(a2q0, 0.f) * fw;
    float r1v = fmaxf(a2q1, 0.f) * fw;
#pragma unroll
    for (int off = 16; off > 0; off >>= 1) {
        r0v += __shfl_down(r0v, off, 32);   // reduce within half-wave
        r1v += __shfl_down(r1v, off, 32);
    }
    if (tc == 0) {
        float fb = fcb[0];
        out[r0 + rr + 0] = r0v + fb;
        out[r0 + rr + 1] = r1v + fb;
    }
}

extern "C" void kernel_launch(void* const* d_in, const int* in_sizes, int n_in,
                              void* d_out, int out_size, void* d_ws, size_t ws_size,
                              hipStream_t stream) {
    const float* x   = (const float*)d_in[0];
    const int*   ei  = (const int*)d_in[1];
    const float* W1  = (const float*)d_in[2];
    const float* b1  = (const float*)d_in[3];
    const float* W2  = (const float*)d_in[4];
    const float* b2  = (const float*)d_in[5];
    const float* c1w = (const float*)d_in[6];
    const float* c1b = (const float*)d_in[7];
    const float* c2w = (const float*)d_in[8];
    const float* c2b = (const float*)d_in[9];
    const float* fcw = (const float*)d_in[10];
    const float* fcb = (const float*)d_in[11];
    float* out = (float*)d_out;

    const int E = in_sizes[1] / 2;
    const int* src = ei;
    const int* dst = ei + E;

    // ---- workspace layout (graph arrays: N_NODES rows only, 7.7 MB each) ----
    const size_t SG = (size_t)N_NODES * RSTRIDE;
    int*    cnt      = (int*)d_ws;                 // 10240
    int*    row_ptr  = cnt + 10240;                // 10240
    int*    fill_pos = row_ptr + 10240;            // 10240
    int2*   edges    = (int2*)(fill_pos + 10240);  // E records
    float*  dinv     = (float*)(edges + E);        // 10240
    float4* w1p      = (float4*)(dinv + 10240);    // 2048 float4 (16B-aligned)
    float2* w2p      = (float2*)(w1p + 2048);      // 1024 float2
    float*  mA       = (float*)(w2p + 1024);       // SG
    float*  mB       = mA + SG;                    // SG
    float*  Hb       = mB + SG;                    // SG

    // ---- CSR build + weight packing ----
    hipMemsetAsync(cnt, 0, N_NODES * sizeof(int), stream);
    hist_kernel<<<(E + 255) / 256, 256, 0, stream>>>(dst, cnt, E);
    scan_kernel<<<1, 1024, 0, stream>>>(cnt, row_ptr, fill_pos, dinv);
    fill_kernel<<<(E + 255) / 256, 256, 0, stream>>>(src, dst, dinv, fill_pos, edges, E);
    prep_kernel<<<12, 256, 0, stream>>>(c1w, c2w, w1p, w2p);

    // ---- graph path: rows < 10000 ----
    gemm1_kernel <<<(N_NODES * HID) / 256, 256, 0, stream>>>(x, W1, mA);
    gatherA_kernel<<<(N_NODES * HID) / 256, 256, 0, stream>>>(mA, row_ptr, edges, dinv, b1, W2, mB);
    gatherB_kernel<<<(N_NODES * HID) / 256, 256, 0, stream>>>(mB, row_ptr, edges, dinv, b2, Hb);

    // ---- conv+fc for ALL rows (graph rows read Hb; dense rows from x) ----
    convfc_kernel<<<BN_TOT / 32, 512, 0, stream>>>(Hb, x, W1, b1, W2, b2,
                                                   w1p, c1b, w2p, c2b, fcw, fcb, out);
}

// Round 14
// 162.854 us; speedup vs baseline: 1.5639x; 1.0471x over previous
//
#include <hip/hip_runtime.h>

#define N_NODES 10000
#define BN_TOT  40000
#define HID     64
#define IN_F    16
#define TCH     32
#define NW      12
#define RSTRIDE 192   // floats per row: planes [t=3][ch=64] at +0B, +256B, +512B

// ---------------- histogram of dst (degree = cnt + 1) ------------------------
__global__ void hist_kernel(const int* __restrict__ dst, int* __restrict__ cnt, int E) {
    int e = blockIdx.x * blockDim.x + threadIdx.x;
    if (e < E) atomicAdd(&cnt[dst[e]], 1);
}

// ---------------- single-block exclusive scan over 10000 bins ----------------
__global__ __launch_bounds__(1024) void scan_kernel(const int* __restrict__ cnt,
                                                    int* __restrict__ row_ptr,
                                                    int* __restrict__ fill_pos,
                                                    float* __restrict__ dinv) {
    __shared__ int part[1024];
    int t = threadIdx.x;
    int base = t * 10;
    int s = 0;
#pragma unroll
    for (int k = 0; k < 10; ++k) {
        int b = base + k;
        if (b < N_NODES) s += cnt[b];
    }
    part[t] = s;
    __syncthreads();
    for (int off = 1; off < 1024; off <<= 1) {
        int v = 0;
        if (t >= off) v = part[t - off];
        __syncthreads();
        part[t] += v;
        __syncthreads();
    }
    int running = (t == 0) ? 0 : part[t - 1];
#pragma unroll
    for (int k = 0; k < 10; ++k) {
        int b = base + k;
        if (b < N_NODES) {
            row_ptr[b]  = running;
            fill_pos[b] = running;
            int c = cnt[b];
            dinv[b] = rsqrtf((float)c + 1.0f);
            running += c;
        }
    }
    if (t == 1023) row_ptr[N_NODES] = part[1023];
}

// ---------------- CSR bucket fill: edge record = {src byte offset, ne} -------
__global__ void fill_kernel(const int* __restrict__ src, const int* __restrict__ dst,
                            const float* __restrict__ dinv,
                            int* __restrict__ fill_pos,
                            int2* __restrict__ edges, int E) {
    int e = blockIdx.x * blockDim.x + threadIdx.x;
    if (e >= E) return;
    int s = src[e], d = dst[e];
    int pos = atomicAdd(&fill_pos[d], 1);
    edges[pos] = make_int2(s * (RSTRIDE * 4), __float_as_int(dinv[s] * dinv[d]));
}

// ---------------- pack conv weights: float4 / float2 per (ic, tc) ------------
__global__ void prep_kernel(const float* __restrict__ c1w, const float* __restrict__ c2w,
                            float4* __restrict__ w1p, float2* __restrict__ w2p) {
    int idx = blockIdx.x * blockDim.x + threadIdx.x;   // 3072 threads
    if (idx < 2048) {
        int tc = idx & 31, ic = idx >> 5;
        const float* p = c1w + tc * 192 + ic * 3;
        w1p[idx] = make_float4(p[0], p[1], p[2], 0.f);
    } else {
        int i2 = idx - 2048;
        int tc = i2 & 31, ic = i2 >> 5;
        const float* p = c2w + tc * 96 + ic * 3;
        w2p[i2] = make_float2(p[0], p[1]);
    }
}

// ---------------- GEMM1 (rows < N_NODES): m[n][t][64] = x @ W1 ---------------
__global__ __launch_bounds__(256) void gemm1_kernel(const float* __restrict__ x,
                                                    const float* __restrict__ W1,
                                                    float* __restrict__ m) {
    int idx = blockIdx.x * blockDim.x + threadIdx.x;   // 640,000 threads
    int oc = idx & 63;
    int n = __builtin_amdgcn_readfirstlane(idx >> 6);  // row < 10000, b = 0
    const float* xb = x + (size_t)n * IN_F;
    float s0 = 0.f, s1 = 0.f, s2 = 0.f;
#pragma unroll
    for (int f = 0; f < IN_F; ++f) {
        float wv = W1[f * HID + oc];
        s0 += xb[(size_t)9  * N_NODES * IN_F + f] * wv;
        s1 += xb[(size_t)10 * N_NODES * IN_F + f] * wv;
        s2 += xb[(size_t)11 * N_NODES * IN_F + f] * wv;
    }
    float* mr = m + (size_t)n * RSTRIDE;
    mr[oc] = s0; mr[64 + oc] = s1; mr[128 + oc] = s2;
}

// ---- gatherA (rows < N_NODES): h1 = relu(agg+self+b1); m2 = h1 @ W2 ---------
__global__ __launch_bounds__(256, 8) void gatherA_kernel(
        const float* __restrict__ m, const int* __restrict__ row_ptr,
        const int2* __restrict__ edges,
        const float* __restrict__ dinv, const float* __restrict__ b1,
        const float* __restrict__ W2, float* __restrict__ m2) {
    __shared__ float hs[4][3][HID];
    int gid = blockIdx.x * blockDim.x + threadIdx.x;   // 10000 waves
    int lane = threadIdx.x & 63;
    int wv = threadIdx.x >> 6;
    int row = __builtin_amdgcn_readfirstlane(gid >> 6);
    const int lo0 = lane * 4, lo1 = 256 + lane * 4, lo2 = 512 + lane * 4;
    const char* mrow = (const char*)m + (size_t)row * (RSTRIDE * 4);
    float dv = dinv[row];
    float sn = dv * dv;
    float s0 = sn * *(const float*)(mrow + lo0);
    float s1 = sn * *(const float*)(mrow + lo1);
    float s2 = sn * *(const float*)(mrow + lo2);
    int j = row_ptr[row], end = row_ptr[row + 1];
    for (; j + 3 < end; j += 4) {
        int2 e0 = edges[j], e1 = edges[j + 1], e2 = edges[j + 2], e3 = edges[j + 3];
        const char* q0 = (const char*)m + e0.x;
        const char* q1 = (const char*)m + e1.x;
        const char* q2 = (const char*)m + e2.x;
        const char* q3 = (const char*)m + e3.x;
        float w0 = __int_as_float(e0.y), w1 = __int_as_float(e1.y);
        float w2 = __int_as_float(e2.y), w3 = __int_as_float(e3.y);
        s0 += w0 * *(const float*)(q0 + lo0) + w1 * *(const float*)(q1 + lo0)
            + w2 * *(const float*)(q2 + lo0) + w3 * *(const float*)(q3 + lo0);
        s1 += w0 * *(const float*)(q0 + lo1) + w1 * *(const float*)(q1 + lo1)
            + w2 * *(const float*)(q2 + lo1) + w3 * *(const float*)(q3 + lo1);
        s2 += w0 * *(const float*)(q0 + lo2) + w1 * *(const float*)(q1 + lo2)
            + w2 * *(const float*)(q2 + lo2) + w3 * *(const float*)(q3 + lo2);
    }
    for (; j < end; ++j) {
        int2 e = edges[j];
        const char* q = (const char*)m + e.x;
        float w = __int_as_float(e.y);
        s0 += w * *(const float*)(q + lo0);
        s1 += w * *(const float*)(q + lo1);
        s2 += w * *(const float*)(q + lo2);
    }
    float bb = b1[lane];
    hs[wv][0][lane] = fmaxf(s0 + bb, 0.f);
    hs[wv][1][lane] = fmaxf(s1 + bb, 0.f);
    hs[wv][2][lane] = fmaxf(s2 + bb, 0.f);
    __builtin_amdgcn_wave_barrier();
    const float4* h0v = (const float4*)&hs[wv][0][0];
    const float4* h1v = (const float4*)&hs[wv][1][0];
    const float4* h2v = (const float4*)&hs[wv][2][0];
    float t0 = 0.f, t1 = 0.f, t2 = 0.f;
#pragma unroll
    for (int ic4 = 0; ic4 < 16; ++ic4) {
        float4 h0 = h0v[ic4], h1 = h1v[ic4], h2 = h2v[ic4];
        float wA = W2[(ic4 * 4 + 0) * HID + lane];
        float wB = W2[(ic4 * 4 + 1) * HID + lane];
        float wC = W2[(ic4 * 4 + 2) * HID + lane];
        float wD = W2[(ic4 * 4 + 3) * HID + lane];
        t0 += h0.x * wA + h0.y * wB + h0.z * wC + h0.w * wD;
        t1 += h1.x * wA + h1.y * wB + h1.z * wC + h1.w * wD;
        t2 += h2.x * wA + h2.y * wB + h2.z * wC + h2.w * wD;
    }
    float* m2r = m2 + (size_t)row * RSTRIDE;
    m2r[lane] = t0; m2r[64 + lane] = t1; m2r[128 + lane] = t2;
}

// ---- convfc: wave w handles rows {w, w+10k, w+20k, w+30k} -------------------
// Slot 0 = graph row (2nd-layer edge gather on mB, fused from gatherB).
// Slots 1..3 = dense rows (full chain from x). Every wave mixes 1 latency-bound
// edge loop with ~1500 VALU FMAs -> gather latency hides under conv math.
__global__ __launch_bounds__(512, 4) void convfc_kernel(
        const float* __restrict__ mB, const int* __restrict__ row_ptr,
        const int2* __restrict__ edges,
        const float* __restrict__ dinv, const float* __restrict__ b2,
        const float* __restrict__ x, const float* __restrict__ W1,
        const float* __restrict__ b1, const float* __restrict__ W2,
        const float4* __restrict__ w1p, const float* __restrict__ b1c,
        const float2* __restrict__ w2p, const float* __restrict__ b2c,
        const float* __restrict__ fcw, const float* __restrict__ fcb,
        float* __restrict__ out) {
    __shared__ float4 w1s[2048];            // 32 KB conv1 weights
    __shared__ float  hs[8][4][3][HID];     // [wave][slot][t-plane][ch]  24 KB
    __shared__ float  c1s[8][4][2][TCH];    // [wave][slot][t10/t11][tc]   8 KB
    int t = threadIdx.x;
#pragma unroll
    for (int i = 0; i < 4; ++i) w1s[i * 512 + t] = w1p[i * 512 + t];
    __syncthreads();

    int wv = t >> 6, lane = t & 63;
    int w = __builtin_amdgcn_readfirstlane(blockIdx.x * 8 + wv);   // 0..9999

    // ---- slot 0: graph row w — 2nd GCN layer edge gather over mB ----
    {
        const int lo0 = lane * 4, lo1 = 256 + lane * 4, lo2 = 512 + lane * 4;
        const char* mrow = (const char*)mB + (size_t)w * (RSTRIDE * 4);
        float dv = dinv[w];
        float sn = dv * dv;
        float s0 = sn * *(const float*)(mrow + lo0);
        float s1 = sn * *(const float*)(mrow + lo1);
        float s2 = sn * *(const float*)(mrow + lo2);
        int j = row_ptr[w], end = row_ptr[w + 1];
        for (; j + 3 < end; j += 4) {
            int2 e0 = edges[j], e1 = edges[j + 1], e2 = edges[j + 2], e3 = edges[j + 3];
            const char* q0 = (const char*)mB + e0.x;
            const char* q1 = (const char*)mB + e1.x;
            const char* q2 = (const char*)mB + e2.x;
            const char* q3 = (const char*)mB + e3.x;
            float w0 = __int_as_float(e0.y), w1 = __int_as_float(e1.y);
            float w2 = __int_as_float(e2.y), w3 = __int_as_float(e3.y);
            s0 += w0 * *(const float*)(q0 + lo0) + w1 * *(const float*)(q1 + lo0)
                + w2 * *(const float*)(q2 + lo0) + w3 * *(const float*)(q3 + lo0);
            s1 += w0 * *(const float*)(q0 + lo1) + w1 * *(const float*)(q1 + lo1)
                + w2 * *(const float*)(q2 + lo1) + w3 * *(const float*)(q3 + lo1);
            s2 += w0 * *(const float*)(q0 + lo2) + w1 * *(const float*)(q1 + lo2)
                + w2 * *(const float*)(q2 + lo2) + w3 * *(const float*)(q3 + lo2);
        }
        for (; j < end; ++j) {
            int2 e = edges[j];
            const char* q = (const char*)mB + e.x;
            float ww = __int_as_float(e.y);
            s0 += ww * *(const float*)(q + lo0);
            s1 += ww * *(const float*)(q + lo1);
            s2 += ww * *(const float*)(q + lo2);
        }
        float bb = b2[lane];
        hs[wv][0][0][lane] = fmaxf(s0 + bb, 0.f);
        hs[wv][0][1][lane] = fmaxf(s1 + bb, 0.f);
        hs[wv][0][2][lane] = fmaxf(s2 + bb, 0.f);
    }

    // ---- slots 1..3: dense rows w + k*10000 (b = k), full chain from x ----
    {
        float w1r[16];
#pragma unroll
        for (int f = 0; f < IN_F; ++f) w1r[f] = W1[f * HID + lane];
        float s[9];
#pragma unroll
        for (int k = 1; k <= 3; ++k) {
#pragma unroll
            for (int tt = 0; tt < 3; ++tt) {
                const float* xp = x + ((size_t)(k * NW + 9 + tt) * N_NODES + w) * IN_F;
                float a = 0.f;
#pragma unroll
                for (int f = 0; f < IN_F; ++f) a += xp[f] * w1r[f];  // xp uniform -> s_loads
                s[(k - 1) * 3 + tt] = a;
            }
        }
        float bb1 = b1[lane];
#pragma unroll
        for (int k = 1; k <= 3; ++k) {
            hs[wv][k][0][lane] = fmaxf(s[(k - 1) * 3 + 0] + bb1, 0.f);
            hs[wv][k][1][lane] = fmaxf(s[(k - 1) * 3 + 1] + bb1, 0.f);
            hs[wv][k][2][lane] = fmaxf(s[(k - 1) * 3 + 2] + bb1, 0.f);
        }
        __builtin_amdgcn_wave_barrier();
        float acc[9];
#pragma unroll
        for (int mm = 0; mm < 9; ++mm) acc[mm] = 0.f;
#pragma unroll
        for (int k4 = 0; k4 < 16; ++k4) {
            float wA = W2[(k4 * 4 + 0) * HID + lane];
            float wB = W2[(k4 * 4 + 1) * HID + lane];
            float wC = W2[(k4 * 4 + 2) * HID + lane];
            float wD = W2[(k4 * 4 + 3) * HID + lane];
#pragma unroll
            for (int k = 1; k <= 3; ++k) {
#pragma unroll
                for (int tt = 0; tt < 3; ++tt) {
                    float4 h = ((const float4*)&hs[wv][k][tt][0])[k4];  // broadcast
                    acc[(k - 1) * 3 + tt] += h.x * wA + h.y * wB + h.z * wC + h.w * wD;
                }
            }
        }
        __builtin_amdgcn_wave_barrier();
        float bb2 = b2[lane];
#pragma unroll
        for (int k = 1; k <= 3; ++k) {
            hs[wv][k][0][lane] = fmaxf(acc[(k - 1) * 3 + 0] + bb2, 0.f);
            hs[wv][k][1][lane] = fmaxf(acc[(k - 1) * 3 + 1] + bb2, 0.f);
            hs[wv][k][2][lane] = fmaxf(acc[(k - 1) * 3 + 2] + bb2, 0.f);
        }
    }
    __builtin_amdgcn_wave_barrier();

    // ---- conv1: lane (pos,tc) computes c1[10+pos][tc] for the 4 slots ----
    int pos = lane >> 5, tc = lane & 31;
    int pA = pos, pB = pos + 1, pC = (pos == 0) ? 2 : 0;   // pC data irrelevant at pos=1
    float hCs = (pos == 0) ? 1.f : 0.f;
    float a1[4];
    float bc1 = b1c[tc];
#pragma unroll
    for (int r = 0; r < 4; ++r) a1[r] = bc1;
#pragma unroll
    for (int ic4 = 0; ic4 < 16; ++ic4) {
        float4 wa = w1s[(ic4 * 4 + 0) * 32 + tc];
        float4 wb = w1s[(ic4 * 4 + 1) * 32 + tc];
        float4 wc = w1s[(ic4 * 4 + 2) * 32 + tc];
        float4 wd = w1s[(ic4 * 4 + 3) * 32 + tc];
        float waz = wa.z * hCs, wbz = wb.z * hCs, wcz = wc.z * hCs, wdz = wd.z * hCs;
#pragma unroll
        for (int r = 0; r < 4; ++r) {
            float4 hA = ((const float4*)&hs[wv][r][pA][0])[ic4];
            float4 hB = ((const float4*)&hs[wv][r][pB][0])[ic4];
            float4 hC = ((const float4*)&hs[wv][r][pC][0])[ic4];
            a1[r] += hA.x * wa.x + hB.x * wa.y + hC.x * waz
                   + hA.y * wb.x + hB.y * wb.y + hC.y * wbz
                   + hA.z * wc.x + hB.z * wc.y + hC.z * wcz
                   + hA.w * wd.x + hB.w * wd.y + hC.w * wdz;
        }
    }
#pragma unroll
    for (int r = 0; r < 4; ++r) c1s[wv][r][pos][tc] = fmaxf(a1[r], 0.f);
    __builtin_amdgcn_wave_barrier();

    // ---- conv2 @ t=11 + relu + fc: half-wave pos handles slots {2pos, 2pos+1} ----
    int rr = pos * 2;
    float bc2 = b2c[tc];
    float a2q0 = bc2, a2q1 = bc2;
#pragma unroll
    for (int ic4 = 0; ic4 < 8; ++ic4) {
        float2 w0 = w2p[(ic4 * 4 + 0) * 32 + tc];
        float2 w1 = w2p[(ic4 * 4 + 1) * 32 + tc];
        float2 w2v = w2p[(ic4 * 4 + 2) * 32 + tc];
        float2 w3 = w2p[(ic4 * 4 + 3) * 32 + tc];
        float4 cA0 = ((const float4*)&c1s[wv][rr + 0][0][0])[ic4];
        float4 cB0 = ((const float4*)&c1s[wv][rr + 0][1][0])[ic4];
        float4 cA1 = ((const float4*)&c1s[wv][rr + 1][0][0])[ic4];
        float4 cB1 = ((const float4*)&c1s[wv][rr + 1][1][0])[ic4];
        a2q0 += cA0.x * w0.x + cB0.x * w0.y + cA0.y * w1.x + cB0.y * w1.y
              + cA0.z * w2v.x + cB0.z * w2v.y + cA0.w * w3.x + cB0.w * w3.y;
        a2q1 += cA1.x * w0.x + cB1.x * w0.y + cA1.y * w1.x + cB1.y * w1.y
              + cA1.z * w2v.x + cB1.z * w2v.y + cA1.w * w3.x + cB1.w * w3.y;
    }
    float fw = fcw[tc];
    float r0v = fmaxf(a2q0, 0.f) * fw;
    float r1v = fmaxf(a2q1, 0.f) * fw;
#pragma unroll
    for (int off = 16; off > 0; off >>= 1) {
        r0v += __shfl_down(r0v, off, 32);   // reduce within half-wave
        r1v += __shfl_down(r1v, off, 32);
    }
    if (tc == 0) {
        float fb = fcb[0];
        out[w + (rr + 0) * N_NODES] = r0v + fb;
        out[w + (rr + 1) * N_NODES] = r1v + fb;
    }
}

extern "C" void kernel_launch(void* const* d_in, const int* in_sizes, int n_in,
                              void* d_out, int out_size, void* d_ws, size_t ws_size,
                              hipStream_t stream) {
    const float* x   = (const float*)d_in[0];
    const int*   ei  = (const int*)d_in[1];
    const float* W1  = (const float*)d_in[2];
    const float* b1  = (const float*)d_in[3];
    const float* W2  = (const float*)d_in[4];
    const float* b2  = (const float*)d_in[5];
    const float* c1w = (const float*)d_in[6];
    const float* c1b = (const float*)d_in[7];
    const float* c2w = (const float*)d_in[8];
    const float* c2b = (const float*)d_in[9];
    const float* fcw = (const float*)d_in[10];
    const float* fcb = (const float*)d_in[11];
    float* out = (float*)d_out;

    const int E = in_sizes[1] / 2;
    const int* src = ei;
    const int* dst = ei + E;

    // ---- workspace layout (graph arrays: N_NODES rows only, 7.7 MB each) ----
    const size_t SG = (size_t)N_NODES * RSTRIDE;
    int*    cnt      = (int*)d_ws;                 // 10240
    int*    row_ptr  = cnt + 10240;                // 10240
    int*    fill_pos = row_ptr + 10240;            // 10240
    int2*   edges    = (int2*)(fill_pos + 10240);  // E records
    float*  dinv     = (float*)(edges + E);        // 10240
    float4* w1p      = (float4*)(dinv + 10240);    // 2048 float4 (16B-aligned)
    float2* w2p      = (float2*)(w1p + 2048);      // 1024 float2
    float*  mA       = (float*)(w2p + 1024);       // SG
    float*  mB       = mA + SG;                    // SG

    // ---- CSR build + weight packing ----
    hipMemsetAsync(cnt, 0, N_NODES * sizeof(int), stream);
    hist_kernel<<<(E + 255) / 256, 256, 0, stream>>>(dst, cnt, E);
    scan_kernel<<<1, 1024, 0, stream>>>(cnt, row_ptr, fill_pos, dinv);
    fill_kernel<<<(E + 255) / 256, 256, 0, stream>>>(src, dst, dinv, fill_pos, edges, E);
    prep_kernel<<<12, 256, 0, stream>>>(c1w, c2w, w1p, w2p);

    // ---- graph path layer 1: rows < 10000 ----
    gemm1_kernel <<<(N_NODES * HID) / 256, 256, 0, stream>>>(x, W1, mA);
    gatherA_kernel<<<(N_NODES * HID) / 256, 256, 0, stream>>>(mA, row_ptr, edges, dinv, b1, W2, mB);

    // ---- fused: 2nd-layer gather (graph rows) + dense chain + conv + fc ----
    convfc_kernel<<<N_NODES / 8, 512, 0, stream>>>(mB, row_ptr, edges, dinv, b2,
                                                   x, W1, b1, W2,
                                                   w1p, c1b, w2p, c2b, fcw, fcb, out);
}